// Round 1
// baseline (467.932 us; speedup 1.0000x reference)
//
#include <hip/hip_runtime.h>
#include <hip/hip_bf16.h>

#define NN 50000
#define EE 800000
#define NEG 0.2f

using u32 = unsigned int;

__device__ __forceinline__ u32 fkey(float f){
  u32 u = __float_as_uint(f);
  return (u & 0x80000000u) ? ~u : (u | 0x80000000u);
}
__device__ __forceinline__ float funkey(u32 u){
  return (u & 0x80000000u) ? __uint_as_float(u & 0x7fffffffu) : __uint_as_float(~u);
}

// ---- K0: tiny precompute: Wtilde[16][4], cvec[64] ----
__global__ void k_pre(const float* __restrict__ W_edge, const float* __restrict__ att_edge,
                      const float* __restrict__ W_c, const float* __restrict__ b_c,
                      const float* __restrict__ ns, float* __restrict__ Wt, float* __restrict__ cvec){
  int t = threadIdx.x;
  if (t < 64){
    int d = t >> 2, h = t & 3;
    float s = 0.f;
    for (int c = 0; c < 64; c++) s += W_edge[d*256 + h*64 + c] * att_edge[h*64 + c];
    Wt[d*4 + h] = s;
  } else if (t < 128){
    int j = t - 64;
    float s = b_c[j];
    for (int d = 0; d < 16; d++) s += ns[d >> 1] * W_c[(64 + d)*64 + j];
    cvec[j] = s;
  }
}

// ---- K1: xs = x @ W_gat  (fp32 compute, bf16 store), 64x256 tile ----
#define BM 64
#define BK 16
__global__ __launch_bounds__(256) void k_gemm(const float* __restrict__ x,
                                              const float* __restrict__ Wg,
                                              __hip_bfloat16* __restrict__ xs){
  __shared__ float As[BK][BM];
  __shared__ float Bs[BK*256];
  int tid = threadIdx.x;
  int n0 = blockIdx.x * BM;
  int tc = tid & 31, tr = tid >> 5;
  float acc[8][8];
  #pragma unroll
  for (int i = 0; i < 8; i++)
    #pragma unroll
    for (int j = 0; j < 8; j++) acc[i][j] = 0.f;

  for (int k0 = 0; k0 < 128; k0 += BK){
    {
      int r = tid >> 2, kq = (tid & 3) * 4;
      int n = n0 + r; if (n >= NN) n = NN - 1;
      float4 v = *(const float4*)(x + (size_t)n*128 + k0 + kq);
      As[kq+0][r] = v.x; As[kq+1][r] = v.y; As[kq+2][r] = v.z; As[kq+3][r] = v.w;
    }
    #pragma unroll
    for (int i = 0; i < 4; i++){
      int f4 = i*256 + tid;               // 1024 float4 total
      *(float4*)&Bs[f4*4] = *(const float4*)(Wg + (size_t)k0*256 + f4*4);
    }
    __syncthreads();
    #pragma unroll
    for (int kk = 0; kk < BK; kk++){
      float a[8], b[8];
      float4 a0 = *(float4*)&As[kk][tr*8];
      float4 a1 = *(float4*)&As[kk][tr*8 + 4];
      float4 b0 = *(float4*)&Bs[kk*256 + tc*8];
      float4 b1 = *(float4*)&Bs[kk*256 + tc*8 + 4];
      a[0]=a0.x;a[1]=a0.y;a[2]=a0.z;a[3]=a0.w;a[4]=a1.x;a[5]=a1.y;a[6]=a1.z;a[7]=a1.w;
      b[0]=b0.x;b[1]=b0.y;b[2]=b0.z;b[3]=b0.w;b[4]=b1.x;b[5]=b1.y;b[6]=b1.z;b[7]=b1.w;
      #pragma unroll
      for (int i = 0; i < 8; i++)
        #pragma unroll
        for (int j = 0; j < 8; j++) acc[i][j] += a[i]*b[j];
    }
    __syncthreads();
  }
  #pragma unroll
  for (int i = 0; i < 8; i++){
    int n = n0 + tr*8 + i;
    if (n < NN){
      alignas(16) __hip_bfloat16 tmp[8];
      #pragma unroll
      for (int j = 0; j < 8; j++) tmp[j] = __float2bfloat16(acc[i][j]);
      *(uint4*)(xs + (size_t)n*256 + tc*8) = *(uint4*)tmp;
    }
  }
}

// ---- K1b: a_src/a_dst per node (wave per node) ----
__global__ __launch_bounds__(256) void k_adot(const __hip_bfloat16* __restrict__ xs,
                                              const float* __restrict__ att_src,
                                              const float* __restrict__ att_dst,
                                              float* __restrict__ a_src, float* __restrict__ a_dst){
  int wid = (blockIdx.x * blockDim.x + threadIdx.x) >> 6;
  int lane = threadIdx.x & 63;
  if (wid >= NN) return;
  #pragma unroll
  for (int h = 0; h < 4; h++){
    float v = __bfloat162float(xs[(size_t)wid*256 + h*64 + lane]);
    float s = v * att_src[h*64 + lane];
    float d = v * att_dst[h*64 + lane];
    #pragma unroll
    for (int off = 32; off; off >>= 1){
      s += __shfl_down(s, off);
      d += __shfl_down(d, off);
    }
    if (lane == 0){ a_src[wid*4 + h] = s; a_dst[wid*4 + h] = d; }
  }
}

// ---- K2: per-edge logits + leaky_relu + atomic segment max + degree histogram ----
__global__ __launch_bounds__(256) void k_edge(const float* __restrict__ qraw,
        const float* __restrict__ eattr, const int* __restrict__ eidx,
        const float* __restrict__ Wq1, const float* __restrict__ bq1,
        const float* __restrict__ Wq2, const float* __restrict__ bq2,
        const float* __restrict__ Wt,
        const float* __restrict__ a_src, const float* __restrict__ a_dst,
        float* __restrict__ alpha, u32* __restrict__ amaxk, u32* __restrict__ deg){
  __shared__ float sWq1[32], sbq1[8], sWq2[128], sbq2[16], sWt[64];
  int tid = threadIdx.x;
  if (tid < 32) sWq1[tid] = Wq1[tid];
  else if (tid < 40)  sbq1[tid-32]  = bq1[tid-32];
  else if (tid < 168) sWq2[tid-40]  = Wq2[tid-40];
  else if (tid < 184) sbq2[tid-168] = bq2[tid-168];
  else if (tid < 248) sWt[tid-184]  = Wt[tid-184];
  __syncthreads();
  int e = blockIdx.x*256 + tid;
  if (e >= EE) return;

  float4 qr = *(const float4*)(qraw + (size_t)e*4);
  float t1[8];
  #pragma unroll
  for (int j = 0; j < 8; j++){
    float s = sbq1[j] + qr.x*sWq1[j] + qr.y*sWq1[8+j] + qr.z*sWq1[16+j] + qr.w*sWq1[24+j];
    t1[j] = fmaxf(s, 0.f);
  }
  float ae[4] = {0.f,0.f,0.f,0.f};
  const float* ea = eattr + (size_t)e*16;
  #pragma unroll
  for (int d = 0; d < 16; d++){
    float q = sbq2[d];
    #pragma unroll
    for (int j = 0; j < 8; j++) q += t1[j]*sWq2[j*16 + d];
    float v = ea[d] + q;
    #pragma unroll
    for (int h = 0; h < 4; h++) ae[h] += v * sWt[d*4 + h];
  }
  int src = eidx[e], dst = eidx[EE + e];
  float4 as4 = *(const float4*)(a_src + (size_t)src*4);
  float4 ad4 = *(const float4*)(a_dst + (size_t)dst*4);
  float av[4] = {as4.x + ad4.x + ae[0], as4.y + ad4.y + ae[1],
                 as4.z + ad4.z + ae[2], as4.w + ad4.w + ae[3]};
  float4 out;
  float* po = (float*)&out;
  #pragma unroll
  for (int h = 0; h < 4; h++){
    float a = av[h];
    a = (a >= 0.f) ? a : NEG*a;
    po[h] = a;
    atomicMax(&amaxk[(size_t)dst*4 + h], fkey(a));
  }
  *(float4*)(alpha + (size_t)e*4) = out;
  atomicAdd(&deg[dst], 1u);
}

// ---- K3a/K3b: two-level exclusive scan of deg -> offs ----
__global__ __launch_bounds__(1024) void k_scan1(const u32* __restrict__ deg,
                                                u32* __restrict__ offs, u32* __restrict__ bsum){
  __shared__ u32 sd[1024];
  int t = threadIdx.x;
  int i = blockIdx.x*1024 + t;
  u32 v = (i < NN) ? deg[i] : 0u;
  sd[t] = v; __syncthreads();
  for (int off = 1; off < 1024; off <<= 1){
    u32 u = (t >= off) ? sd[t-off] : 0u;
    __syncthreads();
    sd[t] += u;
    __syncthreads();
  }
  if (i < NN) offs[i] = sd[t] - v;
  if (t == 1023) bsum[blockIdx.x] = sd[1023];
}

__global__ __launch_bounds__(1024) void k_scan2(u32* __restrict__ offs, const u32* __restrict__ bsum){
  int b = blockIdx.x;
  u32 p = 0;
  for (int j = 0; j < b; j++) p += bsum[j];
  int i = b*1024 + threadIdx.x;
  if (i < NN) offs[i] += p;
  if (i == NN-1){
    u32 tot = p;
    for (int j = b; j < 49; j++) tot += bsum[j];
    offs[NN] = tot;
  }
}

// ---- K4: scatter edge ids into CSR order ----
__global__ __launch_bounds__(256) void k_scatter(const int* __restrict__ eidx,
        const u32* __restrict__ offs, u32* __restrict__ cnt, u32* __restrict__ eperm){
  int e = blockIdx.x*256 + threadIdx.x;
  if (e >= EE) return;
  int dst = eidx[EE + e];
  u32 pos = offs[dst] + atomicAdd(&cnt[dst], 1u);
  eperm[pos] = (u32)e;
}

// ---- K5: per-node aggregation (wave per node, lane = channel) + fused final GEMM ----
__global__ __launch_bounds__(256) void k_agg(const __hip_bfloat16* __restrict__ xs,
        const int* __restrict__ eidx, const u32* __restrict__ eperm, const u32* __restrict__ offs,
        const float* __restrict__ alpha, const u32* __restrict__ amaxk,
        const float* __restrict__ b_gat, const float* __restrict__ W_c,
        const float* __restrict__ cvec, float* __restrict__ out){
  __shared__ float sW[64*64];
  __shared__ float scv[64];
  __shared__ float sbg[64];
  __shared__ float sxc[4][64];
  int tid = threadIdx.x;
  for (int i = tid; i < 4096; i += 256) sW[i] = W_c[i];
  if (tid < 64){ scv[tid] = cvec[tid]; sbg[tid] = b_gat[tid]; }
  __syncthreads();

  int w = tid >> 6, lane = tid & 63;
  int n = blockIdx.x*4 + w;   // grid is exactly NN/4
  u32 p0 = offs[n], p1 = offs[n+1];
  float m0 = funkey(amaxk[(size_t)n*4+0]);
  float m1 = funkey(amaxk[(size_t)n*4+1]);
  float m2 = funkey(amaxk[(size_t)n*4+2]);
  float m3 = funkey(amaxk[(size_t)n*4+3]);
  float acc0=0.f, acc1=0.f, acc2=0.f, acc3=0.f;
  float d0=0.f, d1=0.f, d2=0.f, d3=0.f;
  for (u32 p = p0; p < p1; p++){
    u32 e = eperm[p];
    int src = eidx[e];
    float4 ar = *(const float4*)(alpha + (size_t)e*4);
    float e0 = __expf(ar.x - m0);
    float e1 = __expf(ar.y - m1);
    float e2 = __expf(ar.z - m2);
    float e3 = __expf(ar.w - m3);
    const __hip_bfloat16* row = xs + (size_t)src*256;
    acc0 += e0 * __bfloat162float(row[lane]);
    acc1 += e1 * __bfloat162float(row[64  + lane]);
    acc2 += e2 * __bfloat162float(row[128 + lane]);
    acc3 += e3 * __bfloat162float(row[192 + lane]);
    d0 += e0; d1 += e1; d2 += e2; d3 += e3;
  }
  float s = 0.f;
  if (d0 > 0.f) s += acc0/d0;
  if (d1 > 0.f) s += acc1/d1;
  if (d2 > 0.f) s += acc2/d2;
  if (d3 > 0.f) s += acc3/d3;
  float xc = 0.25f*s + sbg[lane];
  sxc[w][lane] = xc;
  __syncthreads();

  float o = scv[lane];
  #pragma unroll 8
  for (int c = 0; c < 64; c++) o += sxc[w][c] * sW[c*64 + lane];
  out[(size_t)n*64 + lane] = fmaxf(o, 0.f);
}

extern "C" void kernel_launch(void* const* d_in, const int* in_sizes, int n_in,
                              void* d_out, int out_size, void* d_ws, size_t ws_size,
                              hipStream_t stream){
  const float* x       = (const float*)d_in[0];
  const int*   eidx    = (const int*)d_in[1];
  const float* eattr   = (const float*)d_in[2];
  const float* qraw    = (const float*)d_in[3];
  const float* ns      = (const float*)d_in[4];
  const float* Wg      = (const float*)d_in[5];
  const float* att_src = (const float*)d_in[6];
  const float* att_dst = (const float*)d_in[7];
  const float* W_edge  = (const float*)d_in[8];
  const float* att_edge= (const float*)d_in[9];
  const float* b_gat   = (const float*)d_in[10];
  const float* Wq1     = (const float*)d_in[11];
  const float* bq1     = (const float*)d_in[12];
  const float* Wq2     = (const float*)d_in[13];
  const float* bq2     = (const float*)d_in[14];
  const float* W_c     = (const float*)d_in[15];
  const float* b_c     = (const float*)d_in[16];
  float* out = (float*)d_out;

  char* ws = (char*)d_ws;
  __hip_bfloat16* xs = (__hip_bfloat16*)ws;            // 25,600,000 B
  float* a_src = (float*)(ws + 25600000);              //    800,000 B
  float* a_dst = (float*)(ws + 26400000);              //    800,000 B
  float* alpha = (float*)(ws + 27200000);              // 12,800,000 B
  u32* amaxk   = (u32*)(ws + 40000000);                //    800,000 B
  u32* deg     = (u32*)(ws + 40800000);                //    200,000 B
  u32* offs    = (u32*)(ws + 41000000);                //    200,192 B (N+1 + pad)
  u32* cnt     = (u32*)(ws + 41200192);                //    200,000 B
  u32* eperm   = (u32*)(ws + 41400192);                //  3,200,000 B
  u32* bsum    = (u32*)(ws + 44600192);                //        256 B
  float* Wt    = (float*)(ws + 44600448);              //        256 B
  float* cvec  = (float*)(ws + 44600704);              //        256 B

  hipMemsetAsync(amaxk, 0, 800000, stream);
  hipMemsetAsync(deg,   0, 200000, stream);
  hipMemsetAsync(cnt,   0, 200000, stream);

  k_pre    <<<1,     128, 0, stream>>>(W_edge, att_edge, W_c, b_c, ns, Wt, cvec);
  k_gemm   <<<782,   256, 0, stream>>>(x, Wg, xs);
  k_adot   <<<12500, 256, 0, stream>>>(xs, att_src, att_dst, a_src, a_dst);
  k_edge   <<<3125,  256, 0, stream>>>(qraw, eattr, eidx, Wq1, bq1, Wq2, bq2, Wt,
                                       a_src, a_dst, alpha, amaxk, deg);
  k_scan1  <<<49,   1024, 0, stream>>>(deg, offs, bsum);
  k_scan2  <<<49,   1024, 0, stream>>>(offs, bsum);
  k_scatter<<<3125,  256, 0, stream>>>(eidx, offs, cnt, eperm);
  k_agg    <<<12500, 256, 0, stream>>>(xs, eidx, eperm, offs, alpha, amaxk,
                                       b_gat, W_c, cvec, out);
}

// Round 2
// 281.025 us; speedup vs baseline: 1.6651x; 1.6651x over previous
//
#include <hip/hip_runtime.h>
#include <hip/hip_bf16.h>

#define NN 50000
#define EE 800000
#define NEG 0.2f

using u32 = unsigned int;

// ---- K0: tiny precompute: Wtilde[16][4], cvec[64] ----
__global__ void k_pre(const float* __restrict__ W_edge, const float* __restrict__ att_edge,
                      const float* __restrict__ W_c, const float* __restrict__ b_c,
                      const float* __restrict__ ns, float* __restrict__ Wt, float* __restrict__ cvec){
  int t = threadIdx.x;
  if (t < 64){
    int d = t >> 2, h = t & 3;
    float s = 0.f;
    for (int c = 0; c < 64; c++) s += W_edge[d*256 + h*64 + c] * att_edge[h*64 + c];
    Wt[d*4 + h] = s;
  } else if (t < 128){
    int j = t - 64;
    float s = b_c[j];
    for (int d = 0; d < 16; d++) s += ns[d >> 1] * W_c[(64 + d)*64 + j];
    cvec[j] = s;
  }
}

// ---- K1: xs = x @ W_gat (fp32 compute, bf16 store) + fused a_src/a_dst epilogue ----
#define BM 64
#define BK 16
__global__ __launch_bounds__(256) void k_gemm(const float* __restrict__ x,
                                              const float* __restrict__ Wg,
                                              const float* __restrict__ att_src,
                                              const float* __restrict__ att_dst,
                                              __hip_bfloat16* __restrict__ xs,
                                              float* __restrict__ a_src,
                                              float* __restrict__ a_dst){
  __shared__ float As[BK][BM];
  __shared__ float Bs[BK*256];
  int tid = threadIdx.x;
  int n0 = blockIdx.x * BM;
  int tc = tid & 31, tr = tid >> 5;
  int h  = tc >> 3;            // head for this thread's 8 cols
  int co = (tc & 7) * 8;       // in-head col offset
  float4 as0 = *(const float4*)(att_src + h*64 + co);
  float4 as1 = *(const float4*)(att_src + h*64 + co + 4);
  float4 ad0 = *(const float4*)(att_dst + h*64 + co);
  float4 ad1 = *(const float4*)(att_dst + h*64 + co + 4);

  float acc[8][8];
  #pragma unroll
  for (int i = 0; i < 8; i++)
    #pragma unroll
    for (int j = 0; j < 8; j++) acc[i][j] = 0.f;

  for (int k0 = 0; k0 < 128; k0 += BK){
    {
      int r = tid >> 2, kq = (tid & 3) * 4;
      int n = n0 + r; if (n >= NN) n = NN - 1;
      float4 v = *(const float4*)(x + (size_t)n*128 + k0 + kq);
      As[kq+0][r] = v.x; As[kq+1][r] = v.y; As[kq+2][r] = v.z; As[kq+3][r] = v.w;
    }
    #pragma unroll
    for (int i = 0; i < 4; i++){
      int f4 = i*256 + tid;
      *(float4*)&Bs[f4*4] = *(const float4*)(Wg + (size_t)k0*256 + f4*4);
    }
    __syncthreads();
    #pragma unroll
    for (int kk = 0; kk < BK; kk++){
      float a[8], b[8];
      float4 a0 = *(float4*)&As[kk][tr*8];
      float4 a1 = *(float4*)&As[kk][tr*8 + 4];
      float4 b0 = *(float4*)&Bs[kk*256 + tc*8];
      float4 b1 = *(float4*)&Bs[kk*256 + tc*8 + 4];
      a[0]=a0.x;a[1]=a0.y;a[2]=a0.z;a[3]=a0.w;a[4]=a1.x;a[5]=a1.y;a[6]=a1.z;a[7]=a1.w;
      b[0]=b0.x;b[1]=b0.y;b[2]=b0.z;b[3]=b0.w;b[4]=b1.x;b[5]=b1.y;b[6]=b1.z;b[7]=b1.w;
      #pragma unroll
      for (int i = 0; i < 8; i++)
        #pragma unroll
        for (int j = 0; j < 8; j++) acc[i][j] += a[i]*b[j];
    }
    __syncthreads();
  }
  #pragma unroll
  for (int i = 0; i < 8; i++){
    int n = n0 + tr*8 + i;
    if (n < NN){
      alignas(16) __hip_bfloat16 tmp[8];
      #pragma unroll
      for (int j = 0; j < 8; j++) tmp[j] = __float2bfloat16(acc[i][j]);
      *(uint4*)(xs + (size_t)n*256 + tc*8) = *(uint4*)tmp;
    }
    // fused a_src/a_dst: dot over this thread's 8 cols, reduce over the 8
    // threads (consecutive lanes) covering head h, writer at tc%8==0
    float s = acc[i][0]*as0.x + acc[i][1]*as0.y + acc[i][2]*as0.z + acc[i][3]*as0.w
            + acc[i][4]*as1.x + acc[i][5]*as1.y + acc[i][6]*as1.z + acc[i][7]*as1.w;
    float d = acc[i][0]*ad0.x + acc[i][1]*ad0.y + acc[i][2]*ad0.z + acc[i][3]*ad0.w
            + acc[i][4]*ad1.x + acc[i][5]*ad1.y + acc[i][6]*ad1.z + acc[i][7]*ad1.w;
    s += __shfl_down(s, 4); d += __shfl_down(d, 4);
    s += __shfl_down(s, 2); d += __shfl_down(d, 2);
    s += __shfl_down(s, 1); d += __shfl_down(d, 1);
    if ((tc & 7) == 0 && n < NN){
      a_src[(size_t)n*4 + h] = s;
      a_dst[(size_t)n*4 + h] = d;
    }
  }
}

// ---- K2a: degree histogram ----
__global__ __launch_bounds__(256) void k_deg(const int* __restrict__ dsts, u32* __restrict__ deg){
  int i = blockIdx.x*256 + threadIdx.x;   // i indexes groups of 4 edges
  if (i*4 >= EE) return;
  int4 d4 = *(const int4*)(dsts + (size_t)i*4);
  atomicAdd(&deg[d4.x], 1u);
  atomicAdd(&deg[d4.y], 1u);
  atomicAdd(&deg[d4.z], 1u);
  atomicAdd(&deg[d4.w], 1u);
}

// ---- K3a/K3b: two-level exclusive scan of deg -> offs ----
__global__ __launch_bounds__(1024) void k_scan1(const u32* __restrict__ deg,
                                                u32* __restrict__ offs, u32* __restrict__ bsum){
  __shared__ u32 sd[1024];
  int t = threadIdx.x;
  int i = blockIdx.x*1024 + t;
  u32 v = (i < NN) ? deg[i] : 0u;
  sd[t] = v; __syncthreads();
  for (int off = 1; off < 1024; off <<= 1){
    u32 u = (t >= off) ? sd[t-off] : 0u;
    __syncthreads();
    sd[t] += u;
    __syncthreads();
  }
  if (i < NN) offs[i] = sd[t] - v;
  if (t == 1023) bsum[blockIdx.x] = sd[1023];
}

__global__ __launch_bounds__(1024) void k_scan2(u32* __restrict__ offs, const u32* __restrict__ bsum){
  int b = blockIdx.x;
  u32 p = 0;
  for (int j = 0; j < b; j++) p += bsum[j];
  int i = b*1024 + threadIdx.x;
  if (i < NN) offs[i] += p;
  if (i == NN-1){
    u32 tot = p;
    for (int j = b; j < 49; j++) tot += bsum[j];
    offs[NN] = tot;
  }
}

// ---- K4: per-edge logits + leaky_relu, written DIRECTLY in CSR order ----
__global__ __launch_bounds__(256) void k_edge(const float* __restrict__ qraw,
        const float* __restrict__ eattr, const int* __restrict__ eidx,
        const float* __restrict__ Wq1, const float* __restrict__ bq1,
        const float* __restrict__ Wq2, const float* __restrict__ bq2,
        const float* __restrict__ Wt,
        const float* __restrict__ a_src, const float* __restrict__ a_dst,
        const u32* __restrict__ offs, u32* __restrict__ cnt,
        float* __restrict__ alpha_csr, u32* __restrict__ srcs_csr){
  __shared__ float sWq1[32], sbq1[8], sWq2[128], sbq2[16], sWt[64];
  int tid = threadIdx.x;
  if (tid < 32) sWq1[tid] = Wq1[tid];
  else if (tid < 40)  sbq1[tid-32]  = bq1[tid-32];
  else if (tid < 168) sWq2[tid-40]  = Wq2[tid-40];
  else if (tid < 184) sbq2[tid-168] = bq2[tid-168];
  else if (tid < 248) sWt[tid-184]  = Wt[tid-184];
  __syncthreads();
  int e = blockIdx.x*256 + tid;
  if (e >= EE) return;

  float4 qr = *(const float4*)(qraw + (size_t)e*4);
  float t1[8];
  #pragma unroll
  for (int j = 0; j < 8; j++){
    float s = sbq1[j] + qr.x*sWq1[j] + qr.y*sWq1[8+j] + qr.z*sWq1[16+j] + qr.w*sWq1[24+j];
    t1[j] = fmaxf(s, 0.f);
  }
  float ae[4] = {0.f,0.f,0.f,0.f};
  const float* ea = eattr + (size_t)e*16;
  #pragma unroll
  for (int d = 0; d < 16; d++){
    float q = sbq2[d];
    #pragma unroll
    for (int j = 0; j < 8; j++) q += t1[j]*sWq2[j*16 + d];
    float v = ea[d] + q;
    #pragma unroll
    for (int h = 0; h < 4; h++) ae[h] += v * sWt[d*4 + h];
  }
  int src = eidx[e], dst = eidx[EE + e];
  float4 as4 = *(const float4*)(a_src + (size_t)src*4);
  float4 ad4 = *(const float4*)(a_dst + (size_t)dst*4);
  float4 out;
  float* po = (float*)&out;
  float av[4] = {as4.x + ad4.x + ae[0], as4.y + ad4.y + ae[1],
                 as4.z + ad4.z + ae[2], as4.w + ad4.w + ae[3]};
  #pragma unroll
  for (int hh = 0; hh < 4; hh++){
    float a = av[hh];
    po[hh] = (a >= 0.f) ? a : NEG*a;
  }
  u32 pos = offs[dst] + atomicAdd(&cnt[dst], 1u);
  ((float4*)alpha_csr)[pos] = out;
  srcs_csr[pos] = (u32)src;
}

// ---- K5: per-node online-softmax aggregation + fused head-mean + final GEMM ----
__global__ __launch_bounds__(256) void k_agg(const __hip_bfloat16* __restrict__ xs,
        const u32* __restrict__ srcs_csr, const u32* __restrict__ offs,
        const float* __restrict__ alpha_csr,
        const float* __restrict__ b_gat, const float* __restrict__ W_c,
        const float* __restrict__ cvec, float* __restrict__ out){
  __shared__ float sW[64*64];
  __shared__ float scv[64];
  __shared__ float sbg[64];
  __shared__ float sxc[4][64];
  int tid = threadIdx.x;
  for (int i = tid; i < 4096; i += 256) sW[i] = W_c[i];
  if (tid < 64){ scv[tid] = cvec[tid]; sbg[tid] = b_gat[tid]; }
  __syncthreads();

  int w = tid >> 6, lane = tid & 63;
  int n = blockIdx.x*4 + w;   // grid is exactly NN/4
  u32 p0 = offs[n], p1 = offs[n+1];
  float m0=-INFINITY, m1=-INFINITY, m2=-INFINITY, m3=-INFINITY;
  float acc0=0.f, acc1=0.f, acc2=0.f, acc3=0.f;
  float d0=0.f, d1=0.f, d2=0.f, d3=0.f;
  for (u32 p = p0; p < p1; p++){
    u32 src = srcs_csr[p];
    float4 ar = ((const float4*)alpha_csr)[p];
    const __hip_bfloat16* row = xs + (size_t)src*256;
    float x0 = __bfloat162float(row[lane]);
    float x1 = __bfloat162float(row[64  + lane]);
    float x2 = __bfloat162float(row[128 + lane]);
    float x3 = __bfloat162float(row[192 + lane]);
    // branch-free online softmax (r==1.0 exactly when max unchanged)
    float nm0 = fmaxf(m0, ar.x), r0 = __expf(m0 - nm0), w0 = __expf(ar.x - nm0);
    float nm1 = fmaxf(m1, ar.y), r1 = __expf(m1 - nm1), w1 = __expf(ar.y - nm1);
    float nm2 = fmaxf(m2, ar.z), r2 = __expf(m2 - nm2), w2 = __expf(ar.z - nm2);
    float nm3 = fmaxf(m3, ar.w), r3 = __expf(m3 - nm3), w3 = __expf(ar.w - nm3);
    m0 = nm0; m1 = nm1; m2 = nm2; m3 = nm3;
    acc0 = acc0*r0 + w0*x0; d0 = d0*r0 + w0;
    acc1 = acc1*r1 + w1*x1; d1 = d1*r1 + w1;
    acc2 = acc2*r2 + w2*x2; d2 = d2*r2 + w2;
    acc3 = acc3*r3 + w3*x3; d3 = d3*r3 + w3;
  }
  float s = 0.f;
  if (d0 > 0.f) s += acc0/d0;
  if (d1 > 0.f) s += acc1/d1;
  if (d2 > 0.f) s += acc2/d2;
  if (d3 > 0.f) s += acc3/d3;
  float xc = 0.25f*s + sbg[lane];
  sxc[w][lane] = xc;
  __syncthreads();

  float o = scv[lane];
  #pragma unroll 8
  for (int c = 0; c < 64; c++) o += sxc[w][c] * sW[c*64 + lane];
  out[(size_t)n*64 + lane] = fmaxf(o, 0.f);
}

extern "C" void kernel_launch(void* const* d_in, const int* in_sizes, int n_in,
                              void* d_out, int out_size, void* d_ws, size_t ws_size,
                              hipStream_t stream){
  const float* x       = (const float*)d_in[0];
  const int*   eidx    = (const int*)d_in[1];
  const float* eattr   = (const float*)d_in[2];
  const float* qraw    = (const float*)d_in[3];
  const float* ns      = (const float*)d_in[4];
  const float* Wg      = (const float*)d_in[5];
  const float* att_src = (const float*)d_in[6];
  const float* att_dst = (const float*)d_in[7];
  const float* W_edge  = (const float*)d_in[8];
  const float* att_edge= (const float*)d_in[9];
  const float* b_gat   = (const float*)d_in[10];
  const float* Wq1     = (const float*)d_in[11];
  const float* bq1     = (const float*)d_in[12];
  const float* Wq2     = (const float*)d_in[13];
  const float* bq2     = (const float*)d_in[14];
  const float* W_c     = (const float*)d_in[15];
  const float* b_c     = (const float*)d_in[16];
  float* out = (float*)d_out;

  char* ws = (char*)d_ws;
  __hip_bfloat16* xs = (__hip_bfloat16*)ws;            // 25,600,000 B
  float* a_src    = (float*)(ws + 25600000);           //    800,000 B
  float* a_dst    = (float*)(ws + 26400000);           //    800,000 B
  float* alpha_csr= (float*)(ws + 27200000);           // 12,800,000 B
  u32* srcs_csr   = (u32*)(ws + 40000000);             //  3,200,000 B
  u32* deg        = (u32*)(ws + 43200000);             //    200,000 B
  u32* offs       = (u32*)(ws + 43400000);             //    200,064 B (N+1 + pad)
  u32* cnt        = (u32*)(ws + 43600064);             //    200,000 B
  u32* bsum       = (u32*)(ws + 43800064);             //        256 B
  float* Wt       = (float*)(ws + 43800320);           //        256 B
  float* cvec     = (float*)(ws + 43800576);           //        256 B

  hipMemsetAsync(deg, 0, 200000, stream);
  hipMemsetAsync(cnt, 0, 200000, stream);

  k_pre  <<<1,     128, 0, stream>>>(W_edge, att_edge, W_c, b_c, ns, Wt, cvec);
  k_deg  <<<782,   256, 0, stream>>>(eidx + EE, deg);
  k_gemm <<<782,   256, 0, stream>>>(x, Wg, att_src, att_dst, xs, a_src, a_dst);
  k_scan1<<<49,   1024, 0, stream>>>(deg, offs, bsum);
  k_scan2<<<49,   1024, 0, stream>>>(offs, bsum);
  k_edge <<<3125,  256, 0, stream>>>(qraw, eattr, eidx, Wq1, bq1, Wq2, bq2, Wt,
                                     a_src, a_dst, offs, cnt, alpha_csr, srcs_csr);
  k_agg  <<<12500, 256, 0, stream>>>(xs, srcs_csr, offs, alpha_csr,
                                     b_gat, W_c, cvec, out);
}